// Round 2
// baseline (282.144 us; speedup 1.0000x reference)
//
#include <hip/hip_runtime.h>
#include <math.h>

#define VOX 262144  // 64^3

__device__ __forceinline__ int clampi(int v, int lo, int hi) {
    return v < lo ? lo : (v > hi ? hi : v);
}

__device__ __forceinline__ float fast_tanh(float u) {
    // (e^2u - 1)/(e^2u + 1); clamp keeps e^2u finite (|u|>9 -> tanh==+-1)
    u = fminf(fmaxf(u, -9.f), 9.f);
    float e2 = __expf(2.f * u);
    return (e2 - 1.f) * __builtin_amdgcn_rcpf(e2 + 1.f);
}

// ---- fused prep: feat transpose (coalesced both sides) + stats zero + weight transpose ----
__global__ void k_pre(const float* __restrict__ f, float* __restrict__ ft,
                      const float* __restrict__ w, float* __restrict__ wT,
                      float* __restrict__ stats) {
    int vox = blockIdx.x * 256 + threadIdx.x;
    float v[8];
#pragma unroll
    for (int ci = 0; ci < 8; ci++) v[ci] = f[ci * VOX + vox];  // 8 coalesced reads
    float4* dst = (float4*)(ft + (size_t)vox * 8);             // coalesced 32B/thread writes
    dst[0] = make_float4(v[0], v[1], v[2], v[3]);
    dst[1] = make_float4(v[4], v[5], v[6], v[7]);

    if (blockIdx.x == 0) {
        if (threadIdx.x < 64) stats[threadIdx.x] = 0.f;  // 36 bn + 8 gn stats
    } else if (blockIdx.x == 1) {
        for (int i = threadIdx.x; i < 3888; i += 256) {  // w[c][ci][k] -> wT[k][ci][c]
            int c = i / 216, r = i % 216;
            int ci = r / 27, k = r % 27;
            wT[(k * 8 + ci) * 18 + c] = w[i];
        }
    }
}

// ---- offset conv (3x3x3, 8 -> 18 ch) + BN sum/sumsq reduction ----
// 2 threads per voxel (wave-aligned halves): half0 = input ch 0-3 (+bias),
// half1 = input ch 4-7. Partials merged via padded LDS. Grid 2048 blocks ->
// 8 blocks/CU -> up to 32 waves/CU for latency hiding.
#define CBODY(CI, WROW)                                              \
    {                                                                \
        float v0 = fp[(CI) * VOX + hc0] * mh0;                       \
        float v1 = fp[(CI) * VOX + h];                               \
        float v2 = fp[(CI) * VOX + hc2] * mh2;                       \
        const float* wp = (WROW) + (CI) * 18;                        \
        _Pragma("unroll")                                            \
        for (int c = 0; c < 18; c++) {                               \
            float a = acc[c];                                        \
            a = fmaf(v0, wp[c], a);                                  \
            a = fmaf(v1, wp[144 + c], a);                            \
            a = fmaf(v2, wp[288 + c], a);                            \
            acc[c] = a;                                              \
        }                                                            \
    }

__global__ __launch_bounds__(256, 8) void k_conv_off(
        const float* __restrict__ f, const float* __restrict__ wT,
        const float* __restrict__ b, float* __restrict__ offs,
        float* __restrict__ stats) {
    int t = threadIdx.x;
    const int half = __builtin_amdgcn_readfirstlane(t >> 7);  // wave-aligned, scalar
    int li = t & 127;
    int idx = blockIdx.x * 128 + li;
    int h = idx & 63, wy = (idx >> 6) & 63, d = idx >> 12;

    int hc0 = h > 0 ? h - 1 : 0;
    int hc2 = h < 63 ? h + 1 : 63;
    float mh0 = h > 0 ? 1.f : 0.f;
    float mh2 = h < 63 ? 1.f : 0.f;

    float acc[18];
    if (half == 0) {
#pragma unroll
        for (int c = 0; c < 18; c++) acc[c] = b[c];
    } else {
#pragma unroll
        for (int c = 0; c < 18; c++) acc[c] = 0.f;
    }

#pragma unroll
    for (int s = 0; s < 9; s++) {
        int kd = s / 3, kw = s % 3;
        int dd = d + kd - 1, ww = wy + kw - 1;
        bool ok = ((unsigned)dd < 64u) & ((unsigned)ww < 64u);  // uniform within wave
        if (ok) {
            const float* fp = f + (dd * 64 + ww) * 64;
            const float* wrow = wT + s * 432;  // compile-time per unrolled s
            if (half == 0) {
                CBODY(0, wrow) CBODY(1, wrow) CBODY(2, wrow) CBODY(3, wrow)
            } else {
                CBODY(4, wrow) CBODY(5, wrow) CBODY(6, wrow) CBODY(7, wrow)
            }
        }
    }

    __shared__ float red[128][19];  // +1 pad -> conflict-free merge
    __shared__ float ls[36];
    if (half) {
#pragma unroll
        for (int c = 0; c < 18; c++) red[li][c] = acc[c];
    }
    if (t < 36) ls[t] = 0.f;
    __syncthreads();
    if (half == 0) {
#pragma unroll
        for (int c = 0; c < 18; c++) acc[c] += red[li][c];
#pragma unroll
        for (int c = 0; c < 18; c++) offs[c * VOX + idx] = acc[c];
#pragma unroll
        for (int c = 0; c < 18; c++) {
            float s = acc[c], q = acc[c] * acc[c];
#pragma unroll
            for (int o = 32; o > 0; o >>= 1) {
                s += __shfl_xor(s, o);
                q += __shfl_xor(q, o);
            }
            if ((t & 63) == 0) {
                atomicAdd(&ls[c], s);
                atomicAdd(&ls[18 + c], q);
            }
        }
    }
    __syncthreads();
    if (t < 36) atomicAdd(&stats[t], ls[t]);
}

// ---- main: BN affine + fast tanh + center-out cumsum + bilinear(z,y) gather + (1,1,9)
//      conv + GroupNorm stats.  2 threads per voxel: half0 = taps 0-4 (+bias),
//      half1 = taps 5-8. Each half needs only 10 of 18 BN channels. ----
#define TAP(K, ZA, YA)                                                              \
    {                                                                               \
        int xi = h + (K) - 4;                                                       \
        if (xi >= 0 && xi <= 62) {                                                  \
            float z = (float)d + (ZA);                                              \
            float y = (float)wy + (YA);                                             \
            float fz = floorf(z), fy = floorf(y);                                   \
            int iz = (int)fz, iy = (int)fy;                                         \
            int z0 = clampi(iz, 0, 63), z1 = clampi(iz + 1, 0, 63);                 \
            int y0 = clampi(iy, 0, 63), y1 = clampi(iy + 1, 0, 63);                 \
            float wz0 = (float)z1 - z, wz1 = z - (float)z0;                         \
            float wgy0 = (float)y1 - y, wgy1 = y - (float)y0;                       \
            float w00 = wz0 * wgy0, w01 = wz0 * wgy1;                               \
            float w10 = wz1 * wgy0, w11 = wz1 * wgy1;                               \
            const float4* p00 = (const float4*)(ft + (((z0 * 64 + y0) * 64 + xi) << 3)); \
            const float4* p01 = (const float4*)(ft + (((z0 * 64 + y1) * 64 + xi) << 3)); \
            const float4* p10 = (const float4*)(ft + (((z1 * 64 + y0) * 64 + xi) << 3)); \
            const float4* p11 = (const float4*)(ft + (((z1 * 64 + y1) * 64 + xi) << 3)); \
            float4 a00 = p00[0], b00 = p00[1];                                      \
            float4 a01 = p01[0], b01 = p01[1];                                      \
            float4 a10 = p10[0], b10 = p10[1];                                      \
            float4 a11 = p11[0], b11 = p11[1];                                      \
            float v[8];                                                             \
            v[0] = w00 * a00.x + w01 * a01.x + w10 * a10.x + w11 * a11.x;           \
            v[1] = w00 * a00.y + w01 * a01.y + w10 * a10.y + w11 * a11.y;           \
            v[2] = w00 * a00.z + w01 * a01.z + w10 * a10.z + w11 * a11.z;           \
            v[3] = w00 * a00.w + w01 * a01.w + w10 * a10.w + w11 * a11.w;           \
            v[4] = w00 * b00.x + w01 * b01.x + w10 * b10.x + w11 * b11.x;           \
            v[5] = w00 * b00.y + w01 * b01.y + w10 * b10.y + w11 * b11.y;           \
            v[6] = w00 * b00.z + w01 * b01.z + w10 * b10.z + w11 * b11.z;           \
            v[7] = w00 * b00.w + w01 * b01.w + w10 * b10.w + w11 * b11.w;           \
            _Pragma("unroll")                                                       \
            for (int ci = 0; ci < 8; ci++) {                                        \
                _Pragma("unroll")                                                   \
                for (int co = 0; co < 16; co++)                                     \
                    acc[co] = fmaf(v[ci], dw[(co * 8 + ci) * 9 + (K)], acc[co]);    \
            }                                                                       \
        }                                                                           \
    }

__global__ __launch_bounds__(256, 6) void k_main(
        const float* __restrict__ ft, const float* __restrict__ offs,
        const float* __restrict__ stats, const float* __restrict__ bn_g,
        const float* __restrict__ bn_b, const float* __restrict__ dw,
        const float* __restrict__ db, float* __restrict__ out,
        float* __restrict__ gstats) {
    int t = threadIdx.x;
    const int half = __builtin_amdgcn_readfirstlane(t >> 7);  // wave-aligned, scalar
    int li = t & 127;
    int idx = blockIdx.x * 128 + li;
    int h = idx & 63, wy = (idx >> 6) & 63, d = idx >> 12;
    const float inv = 1.f / (float)VOX;

    // BN + tanh for this half's 10 channels: z ch cz0..cz0+4, y ch cz0+9..cz0+13
    const int cz0 = half * 4;  // SGPR -> stats/bn loads stay scalar
    float zt[5], yt[5];
#pragma unroll
    for (int j = 0; j < 5; j++) {
        int cz = cz0 + j, cy = cz + 9;
        float mz = stats[cz] * inv;
        float vz = stats[18 + cz] * inv - mz * mz;
        float rz = rsqrtf(vz + 1e-5f);
        zt[j] = fast_tanh(bn_g[cz] * ((offs[cz * VOX + idx] - mz) * rz) + bn_b[cz]);
        float my = stats[cy] * inv;
        float vy = stats[18 + cy] * inv - my * my;
        float ry = rsqrtf(vy + 1e-5f);
        yt[j] = fast_tanh(bn_g[cy] * ((offs[cy * VOX + idx] - my) * ry) + bn_b[cy]);
    }

    // center-out cumsum, only this half's taps
    float za[5], ya[5];
    if (half == 0) {  // zt[j] = zo[j]; taps 0..4
        za[4] = zt[4];          ya[4] = yt[4];
        za[3] = za[4] + zt[3];  ya[3] = ya[4] + yt[3];
        za[2] = za[3] + zt[2];  ya[2] = ya[3] + yt[2];
        za[1] = za[2] + zt[1];  ya[1] = ya[2] + yt[1];
        za[0] = za[1] + zt[0];  ya[0] = ya[1] + yt[0];
    } else {          // zt[j] = zo[4+j]; taps 5..8 (za[j] <-> tap 5+j)
        za[0] = zt[0] + zt[1];  ya[0] = yt[0] + yt[1];
        za[1] = za[0] + zt[2];  ya[1] = ya[0] + yt[2];
        za[2] = za[1] + zt[3];  ya[2] = ya[1] + yt[3];
        za[3] = za[2] + zt[4];  ya[3] = ya[2] + yt[4];
    }

    float acc[16];
    if (half == 0) {
#pragma unroll
        for (int co = 0; co < 16; co++) acc[co] = db[co];
    } else {
#pragma unroll
        for (int co = 0; co < 16; co++) acc[co] = 0.f;
    }

    if (half == 0) {
        TAP(0, za[0], ya[0])
        TAP(1, za[1], ya[1])
        TAP(2, za[2], ya[2])
        TAP(3, za[3], ya[3])
        TAP(4, za[4], ya[4])
    } else {
        TAP(5, za[0], ya[0])
        TAP(6, za[1], ya[1])
        TAP(7, za[2], ya[2])
        TAP(8, za[3], ya[3])
    }

    __shared__ float red[128][17];  // +1 pad -> conflict-free merge
    __shared__ float ls[8];
    if (half) {
#pragma unroll
        for (int co = 0; co < 16; co++) red[li][co] = acc[co];
    }
    if (t < 8) ls[t] = 0.f;
    __syncthreads();
    if (half == 0) {
#pragma unroll
        for (int co = 0; co < 16; co++) acc[co] += red[li][co];
#pragma unroll
        for (int co = 0; co < 16; co++) out[co * VOX + idx] = acc[co];
        // group-norm stats: 4 groups of 4 channels (waves 0-1 only, full waves)
#pragma unroll
        for (int g = 0; g < 4; g++) {
            float s = acc[4 * g] + acc[4 * g + 1] + acc[4 * g + 2] + acc[4 * g + 3];
            float q = acc[4 * g] * acc[4 * g] + acc[4 * g + 1] * acc[4 * g + 1]
                    + acc[4 * g + 2] * acc[4 * g + 2] + acc[4 * g + 3] * acc[4 * g + 3];
#pragma unroll
            for (int o = 32; o > 0; o >>= 1) {
                s += __shfl_xor(s, o);
                q += __shfl_xor(q, o);
            }
            if ((t & 63) == 0) {
                atomicAdd(&ls[g], s);
                atomicAdd(&ls[4 + g], q);
            }
        }
    }
    __syncthreads();
    if (t < 8) atomicAdd(&gstats[t], ls[t]);
}

// ---- apply GroupNorm + ReLU in place on d_out (float4) ----
__global__ void k_gn(const float* __restrict__ gstats, const float* __restrict__ gn_g,
                     const float* __restrict__ gn_b, float* __restrict__ out) {
    int i = blockIdx.x * 256 + threadIdx.x;  // over 16*VOX/4 float4s
    int c = i >> 16;                         // (i*4)/VOX
    int g = c >> 2;
    const float invn = 1.f / (4.f * (float)VOX);
    float m = gstats[g] * invn;
    float var = gstats[4 + g] * invn - m * m;
    float rs = rsqrtf(var + 1e-5f);
    float gg = gn_g[c], gb = gn_b[c];
    float4 v = ((float4*)out)[i];
    v.x = (v.x - m) * rs * gg + gb; v.x = v.x > 0.f ? v.x : 0.f;
    v.y = (v.y - m) * rs * gg + gb; v.y = v.y > 0.f ? v.y : 0.f;
    v.z = (v.z - m) * rs * gg + gb; v.z = v.z > 0.f ? v.z : 0.f;
    v.w = (v.w - m) * rs * gg + gb; v.w = v.w > 0.f ? v.w : 0.f;
    ((float4*)out)[i] = v;
}

extern "C" void kernel_launch(void* const* d_in, const int* in_sizes, int n_in,
                              void* d_out, int out_size, void* d_ws, size_t ws_size,
                              hipStream_t stream) {
    const float* f    = (const float*)d_in[0];
    const float* offw = (const float*)d_in[1];
    const float* offb = (const float*)d_in[2];
    const float* bng  = (const float*)d_in[3];
    const float* bnb  = (const float*)d_in[4];
    const float* dcnw = (const float*)d_in[5];
    const float* dcnb = (const float*)d_in[6];
    const float* gng  = (const float*)d_in[7];
    const float* gnb  = (const float*)d_in[8];
    float* out = (float*)d_out;

    float* ws    = (float*)d_ws;
    float* ft    = ws;               // 8*VOX floats (featT)
    float* offs  = ws + 8 * VOX;     // 18*VOX floats (raw offset conv)
    float* stats = offs + 18 * VOX;  // 36 bn stats + 8 gn stats
    float* gstats = stats + 36;
    // wT lives in d_out's first 3888 floats: dead until k_main overwrites out.
    float* wT = out;

    hipLaunchKernelGGL(k_pre, dim3(VOX / 256), dim3(256), 0, stream, f, ft, offw, wT, stats);
    hipLaunchKernelGGL(k_conv_off, dim3(VOX / 128), dim3(256), 0, stream,
                       f, wT, offb, offs, stats);
    hipLaunchKernelGGL(k_main, dim3(VOX / 128), dim3(256), 0, stream,
                       ft, offs, stats, bng, bnb, dcnw, dcnb, out, gstats);
    hipLaunchKernelGGL(k_gn, dim3((16 * VOX / 4) / 256), dim3(256), 0, stream,
                       gstats, gng, gnb, out);
}